// Round 11
// baseline (1203.534 us; speedup 1.0000x reference)
//
#include <hip/hip_runtime.h>
#include <hip/hip_bf16.h>

typedef __hip_bfloat16 bf16;
typedef __attribute__((ext_vector_type(8))) short s16x8;   // 8 bf16 (4 VGPR) MFMA A/B frag
typedef __attribute__((ext_vector_type(4))) float f32x4;   // MFMA C/D frag

__device__ __forceinline__ float b2f(bf16 x) { return __bfloat162float(x); }
__device__ __forceinline__ bf16 f2b(float x) { return __float2bfloat16(x); }

__device__ __forceinline__ void gld16(const void* g, void* l) {
  __builtin_amdgcn_global_load_lds((const __attribute__((address_space(1))) unsigned int*)g,
                                   (__attribute__((address_space(3))) unsigned int*)l,
                                   16, 0, 0);
}

#define BARRIER() do { asm volatile("" ::: "memory"); \
                       __builtin_amdgcn_s_barrier();  \
                       asm volatile("" ::: "memory"); } while (0)

// ---------------------------------------------------------------------------
__global__ __launch_bounds__(256) void fill_sentinel(float* out, int n) {
  int idx = blockIdx.x * 256 + threadIdx.x;
  if (idx < n) out[idx] = 100.0f;
}

__global__ __launch_bounds__(64) void zero_zb(bf16* zb) {
  zb[threadIdx.x * 2] = f2b(0.f);
  zb[threadIdx.x * 2 + 1] = f2b(0.f);
}

// ---------------------------------------------------------------------------
// pack conv weights (f32 -> bf16): wpN[s][o][c]; wnp[p][t][ot][c][m]
__global__ __launch_bounds__(256) void pack_w(const float* __restrict__ c0w,
                                              const float* __restrict__ c1w,
                                              const float* __restrict__ lw,
                                              bf16* wp0, bf16* wp1, bf16* wp2, bf16* wnp) {
  const int SEG = 9 * 256 * 256;
  int idx = blockIdx.x * 256 + threadIdx.x;
  if (idx < 3 * SEG) {
    int which = idx / SEG, r = idx % SEG;
    int s = r >> 16, o = (r >> 8) & 255, c = r & 255;
    int ky = s / 3, kx = s - 3 * ky;
    if (which == 0)      wp0[r] = f2b(c0w[(((size_t)o * 768 + 256 + c) * 3 + ky) * 3 + kx]);
    else if (which == 1) wp1[r] = f2b(c1w[(((size_t)o * 256 + c) * 3 + ky) * 3 + kx]);
    else                 wp2[r] = f2b(lw [(((size_t)o * 256 + c) * 3 + ky) * 3 + kx]);
  } else {
    int r = idx - 3 * SEG;             // [p][t][ot][c][m]
    int m = r & 255, c = (r >> 8) & 255, tt = r >> 16;
    int ot = tt % 3, t2 = (tt / 3) % 3, p = tt / 9;
    int ky, kx, cin;
    if (p == 0) { kx = t2; ky = ot; cin = c; }        // node_i block
    else        { ky = t2; kx = ot; cin = 512 + c; }  // node_j block
    wnp[r] = f2b(c0w[(((size_t)m * 768 + cin) * 3 + ky) * 3 + kx]);
  }
}

// ---------------------------------------------------------------------------
// adapter 1x1 (one batch): E[i][j][m] = sum_c aw[m][c]*e[i][j][c] + ab[m]
__global__ __launch_bounds__(256) void adapter_k(const float* __restrict__ e,
                                                 const float* __restrict__ aw,
                                                 const float* __restrict__ ab,
                                                 bf16* __restrict__ E) {
  int i = blockIdx.x;
  int m = threadIdx.x;
  __shared__ float se[256 * 7];
  const size_t rb = (size_t)i * (256 * 7);
  for (int idx = m; idx < 256 * 7; idx += 256) se[idx] = e[rb + idx];
  __syncthreads();
  float w[7];
#pragma unroll
  for (int c = 0; c < 7; ++c) w[c] = aw[m * 7 + c];
  float bias = ab[m];
  bf16* ob = E + (size_t)i * 65536 + m;
  for (int j = 0; j < 256; ++j) {
    const float* ej = se + j * 7;
    float a = bias;
#pragma unroll
    for (int c = 0; c < 7; ++c) a += w[c] * ej[c];
    ob[(size_t)j * 256] = f2b(a);
  }
}

// ---------------------------------------------------------------------------
// node terms: TT[p*3+t][pos][m]; grid = p(2) x t(3) x chunk(64 of 4 positions)
template <typename T>
__global__ __launch_bounds__(256) void node_terms(const T* __restrict__ nd,
                                                  const bf16* __restrict__ wnp,
                                                  float* __restrict__ TT) {
  int bid = blockIdx.x;
  int chunk = bid & 63;
  int t = (bid >> 6) % 3;
  int p = bid / 192;
  int tid = threadIdx.x;
  __shared__ float snd[6][256];
  int pos0 = chunk * 4;
  for (int idx = tid; idx < 6 * 256; idx += 256) {
    int r = idx >> 8, c = idx & 255;
    int gp = pos0 - 1 + r;
    snd[r][c] = (gp >= 0 && gp < 256) ? (float)nd[(size_t)gp * 256 + c] : 0.f;
  }
  __syncthreads();
  float acc[4] = {0.f, 0.f, 0.f, 0.f};
  const bf16* wb = wnp + (size_t)((p * 3 + t) * 3) * 65536 + tid;
  for (int c = 0; c < 256; ++c) {
    float w0 = b2f(wb[(size_t)c * 256]);
    float w1 = b2f(wb[(size_t)(65536 + c * 256)]);
    float w2 = b2f(wb[(size_t)(2 * 65536 + c * 256)]);
#pragma unroll
    for (int ii = 0; ii < 4; ++ii)
      acc[ii] += w0 * snd[ii][c] + w1 * snd[ii + 1][c] + w2 * snd[ii + 2][c];
  }
  float* o = TT + (((size_t)(p * 3 + t) * 256 + pos0) * 256) + tid;
#pragma unroll
  for (int ii = 0; ii < 4; ++ii) o[(size_t)ii * 256] = acc[ii];
}

// ---------------------------------------------------------------------------
// 256x256-tile pipelined implicit-GEMM 3x3 conv.
// r11: FRAGMENT PREFETCH + 2 barriers/K-tile (was 4). Every ds_read issues
// BEFORE the MFMA block it does NOT feed (one phase ahead, into the other
// register set afA/afB, bf0/bf1) so the LDS pipe (~2300cyc/K-tile/CU) runs
// under the matrix pipe (~2480cyc) instead of serializing with it (measured
// 6000cyc/K-tile at r10 = lockstep anti-correlation).
// Ledger unchanged from r10: W(kt+1)x4 @ph1, IN(kt+1)x4 @ph2;
//   gate vmcnt(8)@ph2 (drains IN23(kt), 4 phases old) + BARRIER#1 -> LD afB;
//   gate vmcnt(2)@ph4 (drains W+IN01(kt+1), >=2 phases) + BARRIER#2 ->
//   LD afA/bf0 from next buf.
// WAR audit: every frag ds_read is waitcnt-drained before its consuming MFMA,
// which precedes that wave's next barrier; staging writes occur only after
// that barrier -> one barrier between consumption and overwrite everywhere.
template <int EPI, int F32OUT>
__global__ __launch_bounds__(512, 1)
void conv3x3_k(const bf16* __restrict__ inb, const bf16* __restrict__ wpack,
               const float* __restrict__ bias, void* __restrict__ outv,
               const float* __restrict__ TT, const bf16* __restrict__ zbuf) {
  __shared__ __align__(16) char lds[131072];  // 2 x (32KB input | 32KB weights)
  const int bid = blockIdx.x;                 // 256 = xcd(8) x slot(32)
  const int i = ((bid & 7) << 5) + (bid >> 3);  // 32-row band per XCD
  const int tid = threadIdx.x;
  const int lane = tid & 63, wid = tid >> 6;
  const int wr = wid >> 2, wc = wid & 3;      // 2M x 4N wave grid
  const int lo = lane & 15, hi = lane >> 4;
  const int Gs = tid & 7;

  f32x4 acc00[4][2], acc01[4][2], acc10[4][2], acc11[4][2];
  const f32x4 z = {0.f, 0.f, 0.f, 0.f};
#pragma unroll
  for (int mf = 0; mf < 4; ++mf)
#pragma unroll
    for (int nf = 0; nf < 2; ++nf) { acc00[mf][nf] = z; acc01[mf][nf] = z;
                                     acc10[mf][nf] = z; acc11[mf][nf] = z; }
  s16x8 afA[4][2], afB[4][2], bf0[2][2], bf1[2][2];

  // valid ky taps are a contiguous s-range (i=0 drops ky=0, i=255 drops ky=2)
  const int s_lo = (i == 0) ? 3 : 0;
  const int s_hi = (i == 255) ? 5 : 8;
  const int nt = (s_hi - s_lo + 1) * 4;       // K-tiles of 64 ch

  auto STAGE_IN = [&](int t, int r) {         // input round r: px x=r*64+tid/8
    const int s = s_lo + (t >> 2);
    const int ky = s / 3, kx = s - 3 * ky;
    const int cb = (t & 3) * 64;
    const int x = r * 64 + (tid >> 3);
    const int j = x + kx - 1;
    const int sw = (Gs ^ (x & 7)) << 3;
    const bf16* src = (j >= 0 && j <= 255)
        ? inb + (size_t)(i + ky - 1) * 65536 + ((size_t)j << 8) + cb + sw
        : zbuf + sw;
    gld16(src, lds + (t & 1) * 65536 + ((r * 64 + wid * 8) << 7));
  };
  auto STAGE_W = [&](int t, int r) {          // weight round r: oc o=r*64+tid/8
    const int s = s_lo + (t >> 2);
    const int cb = (t & 3) * 64;
    const int o = r * 64 + (tid >> 3);
    gld16(wpack + ((size_t)(s * 256 + o) << 8) + cb + ((Gs ^ (o & 7)) << 3),
          lds + (t & 1) * 65536 + 32768 + ((r * 64 + wid * 8) << 7));
  };
  auto LD_A = [&](int buf, int mh, s16x8 (&dst)[4][2]) {  // IN rounds mh*2+wr
#pragma unroll
    for (int mf = 0; mf < 4; ++mf)
#pragma unroll
      for (int kk = 0; kk < 2; ++kk) {
        const int x = mh * 128 + wr * 64 + mf * 16 + lo;
        dst[mf][kk] = *(const s16x8*)(lds + buf * 65536 + x * 128 +
                                      (((kk * 4 + hi) ^ (lo & 7)) << 4));
      }
  };
  auto LD_B = [&](int buf, int nh, s16x8 (&dst)[2][2]) {  // W round wc
#pragma unroll
    for (int nf = 0; nf < 2; ++nf)
#pragma unroll
      for (int kk = 0; kk < 2; ++kk) {
        const int o = wc * 64 + nh * 32 + nf * 16 + lo;
        dst[nf][kk] = *(const s16x8*)(lds + buf * 65536 + 32768 + o * 128 +
                                      (((kk * 4 + hi) ^ (lo & 7)) << 4));
      }
  };

#define MMA_Q(ACC, AF, BFR)                                                   \
  __builtin_amdgcn_s_setprio(1);                                              \
  _Pragma("unroll") for (int mf = 0; mf < 4; ++mf)                            \
  _Pragma("unroll") for (int nf = 0; nf < 2; ++nf)                            \
  _Pragma("unroll") for (int kk = 0; kk < 2; ++kk)                            \
    ACC[mf][nf] = __builtin_amdgcn_mfma_f32_16x16x32_bf16(                    \
        AF[mf][kk], BFR[nf][kk], ACC[mf][nf], 0, 0, 0);                       \
  __builtin_amdgcn_s_setprio(0);

  // prologue: stage K-tile 0; gate vmcnt(2) (IN23(0) may stay in flight);
  // preload ph1 fragments (afA = IN rounds 0/1, bf0 = W nh0)
#pragma unroll
  for (int r = 0; r < 4; ++r) STAGE_W(0, r);
#pragma unroll
  for (int r = 0; r < 4; ++r) STAGE_IN(0, r);
  asm volatile("s_waitcnt vmcnt(2)" ::: "memory");
  BARRIER();
  LD_A(0, 0, afA); LD_B(0, 0, bf0);

  for (int kt = 0; kt < nt; ++kt) {
    const int buf = kt & 1;
    const bool pf = (kt + 1 < nt);
    // ph1: MMA(afA,bf0); issue W(kt+1); prefetch bf1 for ph2
    if (pf) { STAGE_W(kt + 1, 0); STAGE_W(kt + 1, 1);
              STAGE_W(kt + 1, 2); STAGE_W(kt + 1, 3); }
    LD_B(buf, 1, bf1);
    MMA_Q(acc00, afA, bf0);
    // ph2: MMA(afA,bf1); issue IN(kt+1); gate+BARRIER#1; prefetch afB for ph3
    if (pf) { STAGE_IN(kt + 1, 0); STAGE_IN(kt + 1, 1);
              STAGE_IN(kt + 1, 2); STAGE_IN(kt + 1, 3); }
    if (pf) asm volatile("s_waitcnt vmcnt(8)" ::: "memory");
    else    asm volatile("s_waitcnt vmcnt(0)" ::: "memory");
    BARRIER();
    LD_A(buf, 1, afB);
    MMA_Q(acc01, afA, bf1);
    // ph3: MMA(afB,bf0) -- all frags in regs
    MMA_Q(acc10, afB, bf0);
    // ph4: gate+BARRIER#2; prefetch next-tile ph1 frags; MMA(afB,bf1)
    if (pf) asm volatile("s_waitcnt vmcnt(2)" ::: "memory");
    BARRIER();
    if (pf) { LD_A(buf ^ 1, 0, afA); LD_B(buf ^ 1, 0, bf0); }
    MMA_Q(acc11, afB, bf1);
  }
#undef MMA_Q

  // epilogue: px j = MH*128 + wr*64 + mf*16 + hi*4 + rr
  bf16* orow = (bf16*)outv + (size_t)i * 65536;
  float* orowf = (float*)outv + (size_t)i * 65536;
#define EPI_Q(ACC, MH, NH)                                                    \
  _Pragma("unroll") for (int mf = 0; mf < 4; ++mf) {                          \
    _Pragma("unroll") for (int nf = 0; nf < 2; ++nf) {                        \
      const int o = wc * 64 + NH * 32 + nf * 16 + lo;                         \
      const float bs = bias[o];                                               \
      float ni0 = 0.f, ni1 = 0.f, ni2 = 0.f;                                  \
      if (EPI) { const float* TI = TT + (size_t)i * 256 + o;                  \
        ni0 = TI[0]; ni1 = TI[65536]; ni2 = TI[2 * 65536]; }                  \
      _Pragma("unroll") for (int rr = 0; rr < 4; ++rr) {                      \
        const int j = MH * 128 + wr * 64 + mf * 16 + hi * 4 + rr;             \
        float v = ACC[mf][nf][rr] + bs;                                       \
        if (EPI) {                                                            \
          v += ni1 + (j > 0 ? ni0 : 0.f) + (j < 255 ? ni2 : 0.f);             \
          const float* TJ = TT + (size_t)3 * 65536 + (size_t)j * 256 + o;     \
          float nj0 = TJ[0], nj1 = TJ[65536], nj2 = TJ[2 * 65536];            \
          v += nj1 + (i > 0 ? nj0 : 0.f) + (i < 255 ? nj2 : 0.f); }           \
        v = fmaxf(v, 0.f);                                                    \
        if (F32OUT) orowf[(size_t)j * 256 + o] = v;                           \
        else        orow[(size_t)j * 256 + o] = f2b(v);                       \
      } } }
  EPI_Q(acc00, 0, 0); EPI_Q(acc01, 0, 1); EPI_Q(acc10, 1, 0); EPI_Q(acc11, 1, 1);
#undef EPI_Q
}

// ---------------------------------------------------------------------------
// fused: att = leaky(1x1(feat)); coeff = softmax_j; nd[i][m] = sum_j coeff*feat
template <int F32OUT>
__global__ __launch_bounds__(256) void att_wsum(const bf16* __restrict__ feat,
                                                const float* __restrict__ aw,
                                                const float* __restrict__ ab,
                                                bf16* __restrict__ ndb,
                                                float* __restrict__ ndf) {
  int i = blockIdx.x;
  int tid = threadIdx.x, lane = tid & 63, w = tid >> 6;
  __shared__ float s_aw[256];
  __shared__ float s_att[256];
  __shared__ float s_red[8];
  s_aw[tid] = aw[tid];
  __syncthreads();
  float a0 = s_aw[lane * 4], a1 = s_aw[lane * 4 + 1];
  float a2 = s_aw[lane * 4 + 2], a3 = s_aw[lane * 4 + 3];
  const bf16* fb = feat + (size_t)i * 65536;
  float abv = ab[0];
  for (int jj = 0; jj < 64; ++jj) {
    int j = w * 64 + jj;
    const bf16* f = fb + (size_t)j * 256 + lane * 4;
    float v = a0 * b2f(f[0]) + a1 * b2f(f[1]) + a2 * b2f(f[2]) + a3 * b2f(f[3]);
#pragma unroll
    for (int mk = 32; mk; mk >>= 1) v += __shfl_xor(v, mk);
    if (lane == 0) { float a = v + abv; s_att[j] = a > 0.f ? a : 0.01f * a; }
  }
  __syncthreads();
  float x = s_att[tid];
  float mx = x;
#pragma unroll
  for (int mk = 32; mk; mk >>= 1) mx = fmaxf(mx, __shfl_xor(mx, mk));
  if (lane == 0) s_red[w] = mx;
  __syncthreads();
  mx = fmaxf(fmaxf(s_red[0], s_red[1]), fmaxf(s_red[2], s_red[3]));
  float e = expf(x - mx);
  float sm = e;
#pragma unroll
  for (int mk = 32; mk; mk >>= 1) sm += __shfl_xor(sm, mk);
  if (lane == 0) s_red[4 + w] = sm;
  __syncthreads();
  sm = s_red[4] + s_red[5] + s_red[6] + s_red[7];
  __syncthreads();
  s_att[tid] = e / sm;
  __syncthreads();
  float acc = 0.f;
  for (int j = 0; j < 256; ++j) acc += s_att[j] * b2f(fb[(size_t)j * 256 + tid]);
  if (F32OUT) ndf[(size_t)i * 256 + tid] = acc;
  else        ndb[(size_t)i * 256 + tid] = f2b(acc);
}

// ---------------------------------------------------------------------------
extern "C" void kernel_launch(void* const* d_in, const int* in_sizes, int n_in,
                              void* d_out, int out_size, void* d_ws, size_t ws_size,
                              hipStream_t stream) {
  const float* edge_feats = (const float*)d_in[0];
  const float* node_feats = (const float*)d_in[1];
  const float* adapter_w  = (const float*)d_in[2];
  const float* adapter_b  = (const float*)d_in[3];
  const float* conv0_w    = (const float*)d_in[4];
  const float* conv0_b    = (const float*)d_in[5];
  const float* conv1_w    = (const float*)d_in[6];
  const float* conv1_b    = (const float*)d_in[7];
  const float* last_w     = (const float*)d_in[8];
  const float* last_b     = (const float*)d_in[9];
  const float* att_w      = (const float*)d_in[10];
  const float* att_b      = (const float*)d_in[11];
  float* out = (float*)d_out;

  char* ws = (char*)d_ws;
  size_t off = 0;
  bf16* Q   = (bf16*)(ws + off); off += (size_t)256 * 256 * 256 * 2;      // 33,554,432
  bf16* WP0 = (bf16*)(ws + off); off += (size_t)9 * 65536 * 2;
  bf16* WP1 = (bf16*)(ws + off); off += (size_t)9 * 65536 * 2;
  bf16* WP2 = (bf16*)(ws + off); off += (size_t)9 * 65536 * 2;
  bf16* WNP = (bf16*)(ws + off); off += (size_t)18 * 65536 * 2;           //  2,359,296
  float* TT = (float*)(ws + off); off += (size_t)2 * 3 * 65536 * 4;       //  1,572,864
  bf16* ND  = (bf16*)(ws + off); off += (size_t)65536 * 2;                //    131,072
  bf16* ZB  = (bf16*)(ws + off); off += 256;                              // known-safe total 41,156,864
  if (ws_size < off) {
    fill_sentinel<<<(out_size + 255) / 256, 256, 0, stream>>>(out, out_size);
    return;
  }

  zero_zb<<<1, 64, 0, stream>>>(ZB);
  pack_w<<<11520, 256, 0, stream>>>(conv0_w, conv1_w, last_w, WP0, WP1, WP2, WNP);

  for (int b = 0; b < 2; ++b) {
    // P: bf16 scratch inside the (f32) edge-out region of batch b
    bf16* P = (bf16*)(out + 131072 + (size_t)b * 16777216);
    float* edge_out = out + 131072 + (size_t)b * 16777216;
    float* node_out = out + (size_t)b * 65536;
    const float* eb = edge_feats + (size_t)b * 458752;
    const float* nb = node_feats + (size_t)b * 65536;

    adapter_k<<<256, 256, 0, stream>>>(eb, adapter_w, adapter_b, P);                 // E  @ P
    // block 1
    node_terms<float><<<384, 256, 0, stream>>>(nb, WNP, TT);
    conv3x3_k<1, 0><<<256, 512, 0, stream>>>(P, WP0, conv0_b, Q, TT, ZB);            // A  @ Q
    conv3x3_k<0, 0><<<256, 512, 0, stream>>>(Q, WP1, conv1_b, P, nullptr, ZB);       // B  @ P
    att_wsum<0><<<256, 256, 0, stream>>>(P, att_w, att_b, ND, nullptr);              // nd1 @ ND
    conv3x3_k<0, 0><<<256, 512, 0, stream>>>(P, WP2, last_b, Q, nullptr, ZB);        // C  @ Q
    // block 2
    node_terms<bf16><<<384, 256, 0, stream>>>(ND, WNP, TT);
    conv3x3_k<1, 0><<<256, 512, 0, stream>>>(Q, WP0, conv0_b, P, TT, ZB);            // D  @ P
    conv3x3_k<0, 0><<<256, 512, 0, stream>>>(P, WP1, conv1_b, Q, nullptr, ZB);       // E2 @ Q
    att_wsum<1><<<256, 256, 0, stream>>>(Q, att_w, att_b, nullptr, node_out);        // node out (f32)
    conv3x3_k<0, 1><<<256, 512, 0, stream>>>(Q, WP2, last_b, edge_out, nullptr, ZB); // edge out (f32)
  }
}